// Round 2
// baseline (840.948 us; speedup 1.0000x reference)
//
#include <hip/hip_runtime.h>
#include <math.h>

typedef _Float16 f16x8 __attribute__((ext_vector_type(8)));
typedef _Float16 f16x4 __attribute__((ext_vector_type(4)));
typedef float    f32x4 __attribute__((ext_vector_type(4)));

#define SEQ   2048
#define DH    64
#define BM    64            // q-rows per block (4 waves x 16 rows)
#define BK    64            // k-chunk per iteration
#define LDSW  68            // 64 + 4 pad (keeps 16B align, breaks pow2 bank stride)
#define LOG2E 1.44269504088896340736f

// ---- pre-pass: convert x2 (f32) to f16 once into workspace ----
extern "C" __global__ __launch_bounds__(256)
void cvt_x2_f16(const float* __restrict__ x2, _Float16* __restrict__ y)
{
    size_t i = ((size_t)blockIdx.x * 256 + threadIdx.x) * 4;
    float4 v = *(const float4*)(x2 + i);
    f16x4 h;
    h[0] = (_Float16)v.x; h[1] = (_Float16)v.y;
    h[2] = (_Float16)v.z; h[3] = (_Float16)v.w;
    *(f16x4*)(y + i) = h;
}

// One wave = 16 q-rows, full Dh=64 (4 n-tiles of 16), flash-style online softmax.
// x1 path: coalesced global -> wave-private LDS -> ds_read_b128 fragments.
// No __syncthreads anywhere (waves share nothing).
// A-frag (16x16x32): A[m=lane&15][k=quad*8+j]; C/D: n=lane&15, m=quad*4+reg.
extern "C" __global__ __launch_bounds__(256, 4)
void softmax_matmul_f16(const float* __restrict__ x1,
                        const _Float16* __restrict__ x2h,
                        float* __restrict__ out)
{
    __shared__ __align__(16) float lds[4][2][16][LDSW];   // 34.8 KB -> 4 blocks/CU

    const int tid  = threadIdx.x;
    const int wave = tid >> 6;
    const int lane = tid & 63;
    const int r    = lane & 15;     // q-row within wave tile / n within n-tile
    const int quad = lane >> 4;     // 0..3

    const int bh   = blockIdx.x >> 5;
    const int qblk = blockIdx.x & 31;
    const int row0 = qblk * BM + wave * 16;

    const float*    x1w  = x1  + ((size_t)bh * SEQ + row0) * SEQ;  // wave's 16-row base
    const _Float16* x2b  = x2h + (size_t)bh * DH * SEQ;            // [64][2048] f16
    float*          obase = out + ((size_t)bh * SEQ + row0) * DH;

    // coalesced-load lane mapping: lane covers (row = i*4+quad, cols lc..lc+3)
    const int lc = (lane & 15) * 4;

    f32x4 acc[4];
#pragma unroll
    for (int t = 0; t < 4; ++t) acc[t] = (f32x4){0.f, 0.f, 0.f, 0.f};

    float m = -INFINITY;
    float l = 0.0f;

    float4 g[4];
#pragma unroll
    for (int i = 0; i < 4; ++i)
        g[i] = *(const float4*)(x1w + (size_t)(i * 4 + quad) * SEQ + lc);

    int buf = 0;
    for (int k0 = 0; k0 < SEQ; k0 += BK) {
        // stash chunk k into wave-private LDS (2-way bank groups only)
#pragma unroll
        for (int i = 0; i < 4; ++i)
            *(float4*)&lds[wave][buf][i * 4 + quad][lc] = g[i];

        // prefetch chunk k+1 (coalesced, one full iteration of latency hiding)
        const int k1 = k0 + BK;
        if (k1 < SEQ) {
#pragma unroll
            for (int i = 0; i < 4; ++i)
                g[i] = *(const float4*)(x1w + (size_t)(i * 4 + quad) * SEQ + k1 + lc);
        }

        // B fragments: direct f16 16B loads from L2-resident converted x2
        f16x8 bf[8];
#pragma unroll
        for (int t = 0; t < 4; ++t) {
            const _Float16* bp = x2b + (size_t)(t * 16 + r) * SEQ + k0 + quad * 8;
            bf[2 * t]     = *(const f16x8*)bp;
            bf[2 * t + 1] = *(const f16x8*)(bp + 32);
        }

        // A fragments from LDS (row r, cols quad*8..+7 and 32+quad*8..+7)
        float4 a0 = *(const float4*)&lds[wave][buf][r][quad * 8];
        float4 a1 = *(const float4*)&lds[wave][buf][r][quad * 8 + 4];
        float4 a2 = *(const float4*)&lds[wave][buf][r][32 + quad * 8];
        float4 a3 = *(const float4*)&lds[wave][buf][r][36 + quad * 8];
        buf ^= 1;

        float xv[16];
        xv[0]  = a0.x; xv[1]  = a0.y; xv[2]  = a0.z; xv[3]  = a0.w;
        xv[4]  = a1.x; xv[5]  = a1.y; xv[6]  = a1.z; xv[7]  = a1.w;
        xv[8]  = a2.x; xv[9]  = a2.y; xv[10] = a2.z; xv[11] = a2.w;
        xv[12] = a3.x; xv[13] = a3.y; xv[14] = a3.z; xv[15] = a3.w;

        // ---- online softmax stats (rows live in lanes {r, r+16, r+32, r+48})
        float cmax = xv[0];
#pragma unroll
        for (int j = 1; j < 16; ++j) cmax = fmaxf(cmax, xv[j]);
        cmax = fmaxf(cmax, __shfl_xor(cmax, 16));
        cmax = fmaxf(cmax, __shfl_xor(cmax, 32));

        const float mnew  = fmaxf(m, cmax);
        const float alpha = __builtin_amdgcn_exp2f((m - mnew) * LOG2E);
        const float sh    = mnew * LOG2E;

        float p[16];
        float rsum = 0.f;
#pragma unroll
        for (int j = 0; j < 16; ++j) {
            p[j] = __builtin_amdgcn_exp2f(__builtin_fmaf(xv[j], LOG2E, -sh));
            rsum += p[j];
        }
        rsum += __shfl_xor(rsum, 16);
        rsum += __shfl_xor(rsum, 32);
        l = l * alpha + rsum;
        m = mnew;

        // rescale accumulators: alpha for C-row quad*4+g lives in lane (quad*4+g)
        float ar[4];
#pragma unroll
        for (int gi = 0; gi < 4; ++gi) ar[gi] = __shfl(alpha, quad * 4 + gi);
#pragma unroll
        for (int t = 0; t < 4; ++t)
#pragma unroll
            for (int gi = 0; gi < 4; ++gi) acc[t][gi] *= ar[gi];

        // A fragments -> fp16
        f16x8 ah0, ah1;
#pragma unroll
        for (int j = 0; j < 8; ++j) {
            ah0[j] = (_Float16)p[j];
            ah1[j] = (_Float16)p[8 + j];
        }

#pragma unroll
        for (int t = 0; t < 4; ++t) {
            acc[t] = __builtin_amdgcn_mfma_f32_16x16x32_f16(ah0, bf[2 * t],     acc[t], 0, 0, 0);
            acc[t] = __builtin_amdgcn_mfma_f32_16x16x32_f16(ah1, bf[2 * t + 1], acc[t], 0, 0, 0);
        }
    }

    // ---- epilogue: divide by l; C layout rows quad*4+g, col t*16+r
    const float rl = 1.0f / l;
    float rlr[4];
#pragma unroll
    for (int gi = 0; gi < 4; ++gi) rlr[gi] = __shfl(rl, quad * 4 + gi);
#pragma unroll
    for (int t = 0; t < 4; ++t)
#pragma unroll
        for (int gi = 0; gi < 4; ++gi)
            obase[(size_t)(quad * 4 + gi) * DH + t * 16 + r] = acc[t][gi] * rlr[gi];
}

extern "C" void kernel_launch(void* const* d_in, const int* in_sizes, int n_in,
                              void* d_out, int out_size, void* d_ws, size_t ws_size,
                              hipStream_t stream)
{
    const float* x1 = (const float*)d_in[0];
    const float* x2 = (const float*)d_in[1];
    float* out = (float*)d_out;
    _Float16* x2h = (_Float16*)d_ws;

    const int bhCount = in_sizes[1] / (DH * SEQ);   // B*H = 32
    const int nEl     = in_sizes[1];                // 4,194,304 floats

    hipLaunchKernelGGL(cvt_x2_f16, dim3(nEl / (256 * 4)), dim3(256), 0, stream, x2, x2h);
    hipLaunchKernelGGL(softmax_matmul_f16, dim3(bhCount * (SEQ / BM)), dim3(256), 0, stream,
                       x1, x2h, out);
}